// Round 3
// 484.691 us; speedup vs baseline: 1.0115x; 1.0115x over previous
//
#include <hip/hip_runtime.h>
#include <math.h>

namespace {
constexpr int Bc   = 4;
constexpr int CATT = 8;
constexpr int Dd   = 48;
constexpr int Hh   = 128;
constexpr int Ww   = 256;
constexpr int CF   = 80;
constexpr int EMB  = 64;
constexpr int Nn   = Hh * Ww;            // 32768
constexpr float SCALE = 0.25f;

// ---- padded-plane layout ----
constexpr int ROWP  = 264;               // 4 left pad + 256 + 4 right pad
constexpr int PLANE = 130 * ROWP;        // 34320 floats per plane (1 halo row top/bot)
constexpr size_t WS_KVQ   = 0;                                    // 4*192*PLANE
constexpr size_t WS_WT    = (size_t)Bc * 192 * PLANE;             // + 80*192
constexpr size_t WS_WOT   = WS_WT + (size_t)CF * 192;             // + 512
constexpr size_t WS_END   = WS_WOT + 512;
constexpr size_t NEED_BYTES = WS_END * 4;

// ---- old (fallback) layout ----
constexpr size_t OWS_KV    = 0;                                   // B*N*128
constexpr size_t OWS_DELTA = (size_t)Bc * Nn * 128;
constexpr size_t OWS_WTKV  = OWS_DELTA + (size_t)Bc * CATT * Nn;
constexpr size_t OWS_WTQ   = OWS_WTKV + (size_t)CF * 128;
}  // namespace

// ===========================================================================
// NEW PATH
// ===========================================================================

// prep: wt[c][192] (Q prescaled | K | V), Wot[e][8] = Wo[a][e].
// Halo zeroing: float4 writes, K/V planes only (Q halo is never read).
__global__ void prep_new_k(const float* __restrict__ Wq,
                           const float* __restrict__ Wk,
                           const float* __restrict__ Wv,
                           const float* __restrict__ Wo,
                           float* __restrict__ wt,
                           float* __restrict__ wot,
                           float* __restrict__ kvq) {
  const int t = blockIdx.x * blockDim.x + threadIdx.x;
  const int stride = gridDim.x * blockDim.x;
  for (int i = t; i < CF * 192; i += stride) {
    const int c = i / 192, o = i % 192;
    float v;
    if (o < 64)       v = Wq[o * CF + c] * SCALE;
    else if (o < 128) v = Wk[(o - 64) * CF + c];
    else              v = Wv[(o - 128) * CF + c];
    wt[i] = v;
  }
  for (int i = t; i < 512; i += stride) {
    const int e = i >> 3, a = i & 7;
    wot[i] = Wo[a * EMB + e];
  }
  // halo per plane as float4: row0 = 66, row129 = 66, rows 1..128 x {cols 0..3,
  // 260..263} = 256  -> 388 float4 per plane; planes 64..191 (K,V) only.
  constexpr int HF4 = 388;
  const float4 z4 = make_float4(0.f, 0.f, 0.f, 0.f);
  for (int i = t; i < Bc * 128 * HF4; i += stride) {
    const int f4 = i % HF4;
    const int pl = i / HF4;
    const size_t base = ((size_t)(pl / 128) * 192 + 64 + (pl % 128)) * PLANE;
    int row, col4;
    if (f4 < 66)        { row = 0;   col4 = f4 * 4; }
    else if (f4 < 132)  { row = 129; col4 = (f4 - 66) * 4; }
    else {
      const int rr = f4 - 132;
      row = (rr >> 1) + 1;
      col4 = (rr & 1) ? 260 : 0;
    }
    *(float4*)&kvq[base + (size_t)row * ROWP + col4] = z4;
  }
}

// QKV projection into padded planes. Block=256, 64-pixel row chunk.
// Thread: 12 outputs x 4 pixels.
__global__ __launch_bounds__(256) void qkv_new_k(const float* __restrict__ feat,
                                                 const float* __restrict__ wt,
                                                 float* __restrict__ kvq) {
  __shared__ float lf[CF][64];
  const int b  = blockIdx.y;
  const int n0 = blockIdx.x * 64;
  const int t  = threadIdx.x;

  const float* fb = feat + (size_t)b * CF * Nn + n0;
  for (int i = t; i < CF * 64; i += 256) {
    const int c = i >> 6, p = i & 63;
    lf[c][p] = fb[(size_t)c * Nn + p];
  }
  __syncthreads();

  const int og = t >> 4;          // 16 groups of 12 outputs
  const int p4 = (t & 15) * 4;

  float acc[12][4];
#pragma unroll
  for (int o = 0; o < 12; ++o)
#pragma unroll
    for (int j = 0; j < 4; ++j) acc[o][j] = 0.f;

  for (int c = 0; c < CF; ++c) {
    const float4 fv = *(const float4*)&lf[c][p4];
    const float fa[4] = {fv.x, fv.y, fv.z, fv.w};
    const float4 w0 = *(const float4*)&wt[c * 192 + og * 12];
    const float4 w1 = *(const float4*)&wt[c * 192 + og * 12 + 4];
    const float4 w2 = *(const float4*)&wt[c * 192 + og * 12 + 8];
    const float wv12[12] = {w0.x, w0.y, w0.z, w0.w, w1.x, w1.y, w1.z, w1.w,
                            w2.x, w2.y, w2.z, w2.w};
#pragma unroll
    for (int o = 0; o < 12; ++o)
#pragma unroll
      for (int j = 0; j < 4; ++j) acc[o][j] = fmaf(wv12[o], fa[j], acc[o][j]);
  }

  const int h = n0 >> 8, w0c = n0 & 255;
  float* bbase = kvq + (size_t)b * 192 * PLANE;
  const int rowoff = (h + 1) * ROWP + (w0c + 4) + p4;
#pragma unroll
  for (int o = 0; o < 12; ++o) {
    const int oo = og * 12 + o;
    *(float4*)&bbase[(size_t)oo * PLANE + rowoff] =
        make_float4(acc[o][0], acc[o][1], acc[o][2], acc[o][3]);
  }
}

// attention core for one head (wave-uniform HD -> compile-time offsets)
template <int HD>
__device__ __forceinline__ void attn_core(const float* __restrict__ kb, int coff,
                                          const float* __restrict__ lwot,
                                          float* __restrict__ part) {
  float q16[16];
#pragma unroll
  for (int i = 0; i < 16; ++i)
    q16[i] = kb[(size_t)(HD * 16 + i) * PLANE + coff];

  float sc[9];
#pragma unroll
  for (int w2 = 0; w2 < 9; ++w2) {
    float s = 0.f;
#pragma unroll
    for (int i = 0; i < 16; ++i) {
      const int f = w2 * 64 + HD * 16 + i;       // compile-time after unroll
      const int e = f / 9, widx = f % 9;
      const int D = (widx / 3 - 1) * ROWP + (widx % 3 - 1);
      s = fmaf(q16[i], kb[(size_t)(64 + e) * PLANE + coff + D], s);
    }
    sc[w2] = s;
  }

  float m = sc[0];
#pragma unroll
  for (int w2 = 1; w2 < 9; ++w2) m = fmaxf(m, sc[w2]);
  float probs[9], ssum = 0.f;
#pragma unroll
  for (int w2 = 0; w2 < 9; ++w2) {
    probs[w2] = __expf(sc[w2] - m);
    ssum += probs[w2];
  }
  const float inv = 1.f / ssum;
#pragma unroll
  for (int w2 = 0; w2 < 9; ++w2) probs[w2] *= inv;

  float ctx[16];
#pragma unroll
  for (int i = 0; i < 16; ++i) {
    float c = 0.f;
#pragma unroll
    for (int w2 = 0; w2 < 9; ++w2) {
      const int f = w2 * 64 + HD * 16 + i;
      const int e = f / 9, widx = f % 9;
      const int D = (widx / 3 - 1) * ROWP + (widx % 3 - 1);
      c = fmaf(probs[w2], kb[(size_t)(128 + e) * PLANE + coff + D], c);
    }
    ctx[i] = c;
  }

#pragma unroll
  for (int a = 0; a < 8; ++a) {
    float p = 0.f;
#pragma unroll
    for (int i = 0; i < 16; ++i)
      p = fmaf(lwot[(HD * 16 + i) * 8 + a], ctx[i], p);
    part[a] = p;
  }
}

// Fused attention + D-broadcast residual add.
// Block=256 (4 waves), wave = head, lanes = 64 consecutive pixels of one row.
// After the head reduction each thread owns s for (px, a = ag*2+k) and streams
// out[b,a,d,px] = attn_vol + (mask ? 0 : s) for all 48 d with nontemporal ops.
__global__ __launch_bounds__(256) void attn_fused_k(const float* __restrict__ kvq,
                                                    const float* __restrict__ wot,
                                                    const float* __restrict__ disp,
                                                    const float* __restrict__ av,
                                                    float* __restrict__ out) {
  __shared__ float lwot[512];
  __shared__ float lpart[4 * 576];   // [hd][px*9 + a], stride 9 kills bank conflicts
  const int b = blockIdx.y;
  const int t = threadIdx.x;
  for (int i = t; i < 512; i += 256) lwot[i] = wot[i];
  __syncthreads();

  const int hd = t >> 6, lane = t & 63;
  const int n = blockIdx.x * 64 + lane;
  const int h = n >> 8, w = n & 255;
  const int coff = (h + 1) * ROWP + (w + 4);
  const float* kb = kvq + (size_t)b * 192 * PLANE;

  float part[8];
  switch (hd) {
    case 0: attn_core<0>(kb, coff, lwot, part); break;
    case 1: attn_core<1>(kb, coff, lwot, part); break;
    case 2: attn_core<2>(kb, coff, lwot, part); break;
    default: attn_core<3>(kb, coff, lwot, part); break;
  }
#pragma unroll
  for (int a = 0; a < 8; ++a) lpart[hd * 576 + lane * 9 + a] = part[a];
  __syncthreads();

  const int px = t & 63, ag = t >> 6;
  const int nn = blockIdx.x * 64 + px;
  const bool zero = disp[(size_t)b * Nn + nn] >= 2.0f;

  float sv[2];
#pragma unroll
  for (int k = 0; k < 2; ++k) {
    const int a = ag * 2 + k;
    const float s = lpart[0 * 576 + px * 9 + a] + lpart[1 * 576 + px * 9 + a] +
                    lpart[2 * 576 + px * 9 + a] + lpart[3 * 576 + px * 9 + a];
    sv[k] = zero ? 0.f : s;
  }

#pragma unroll
  for (int k = 0; k < 2; ++k) {
    const int a = ag * 2 + k;
    const size_t pb = ((size_t)(b * CATT + a) * Dd) * Nn + nn;
    const float* ab = av + pb;
    float* ob = out + pb;
    for (int d0 = 0; d0 < Dd; d0 += 8) {
      float tb[8];
#pragma unroll
      for (int j = 0; j < 8; ++j)
        tb[j] = __builtin_nontemporal_load(ab + (size_t)(d0 + j) * Nn);
#pragma unroll
      for (int j = 0; j < 8; ++j)
        __builtin_nontemporal_store(tb[j] + sv[k], ob + (size_t)(d0 + j) * Nn);
    }
  }
}

// ===========================================================================
// OLD PATH (fallback if ws too small) — identical to the passing R2 kernels
// ===========================================================================
__global__ void prep_weights_k(const float* __restrict__ Wq,
                               const float* __restrict__ Wk,
                               const float* __restrict__ Wv,
                               float* __restrict__ wtkv,
                               float* __restrict__ wtq) {
  const int t = blockIdx.x * blockDim.x + threadIdx.x;
  const int stride = gridDim.x * blockDim.x;
  for (int i = t; i < CF * 128; i += stride) {
    const int c = i >> 7, o = i & 127;
    wtkv[i] = (o < 64) ? Wk[o * CF + c] : Wv[(o - 64) * CF + c];
  }
  for (int i = t; i < CF * 64; i += stride) {
    const int c = i >> 6, e = i & 63;
    wtq[i] = Wq[e * CF + c] * SCALE;
  }
}

__global__ __launch_bounds__(256) void qkv_k(const float* __restrict__ feat,
                                             const float* __restrict__ wtkv,
                                             float* __restrict__ kv) {
  __shared__ float lf[CF][64];
  const int b  = blockIdx.y;
  const int n0 = blockIdx.x * 64;
  const int t  = threadIdx.x;
  const float* fb = feat + (size_t)b * CF * Nn + n0;
  for (int i = t; i < CF * 64; i += 256) {
    const int c = i >> 6, p = i & 63;
    lf[c][p] = fb[(size_t)c * Nn + p];
  }
  __syncthreads();
  const int og = t >> 4;
  const int p4 = (t & 15) * 4;
  float acc[8][4];
#pragma unroll
  for (int o = 0; o < 8; ++o)
#pragma unroll
    for (int j = 0; j < 4; ++j) acc[o][j] = 0.f;
  for (int c = 0; c < CF; ++c) {
    const float4 fv = *(const float4*)&lf[c][p4];
    const float fa[4] = {fv.x, fv.y, fv.z, fv.w};
    const float4 wa = *(const float4*)&wtkv[c * 128 + og * 8];
    const float4 wb = *(const float4*)&wtkv[c * 128 + og * 8 + 4];
    const float wv8[8] = {wa.x, wa.y, wa.z, wa.w, wb.x, wb.y, wb.z, wb.w};
#pragma unroll
    for (int o = 0; o < 8; ++o)
#pragma unroll
      for (int j = 0; j < 4; ++j) acc[o][j] = fmaf(wv8[o], fa[j], acc[o][j]);
  }
  float* outb = kv + ((size_t)b * Nn + n0) * 128;
#pragma unroll
  for (int j = 0; j < 4; ++j) {
    const int p = p4 + j;
    *(float4*)&outb[(size_t)p * 128 + og * 8] =
        make_float4(acc[0][j], acc[1][j], acc[2][j], acc[3][j]);
    *(float4*)&outb[(size_t)p * 128 + og * 8 + 4] =
        make_float4(acc[4][j], acc[5][j], acc[6][j], acc[7][j]);
  }
}

__global__ __launch_bounds__(256) void attn_k(const float* __restrict__ feat,
                                              const float* __restrict__ kvbuf,
                                              const float* __restrict__ wtq,
                                              const float* __restrict__ Wo,
                                              const float* __restrict__ disp,
                                              float* __restrict__ delta) {
  const int b = blockIdx.y;
  const int n = blockIdx.x * 256 + threadIdx.x;
  const int h = n >> 8;
  const int w = n & 255;
  float q[EMB];
#pragma unroll
  for (int e = 0; e < EMB; ++e) q[e] = 0.f;
  {
    const float* fb = feat + (size_t)b * CF * Nn + n;
    for (int c = 0; c < CF; ++c) {
      const float fv = fb[(size_t)c * Nn];
#pragma unroll
      for (int e = 0; e < EMB; ++e) q[e] = fmaf(wtq[c * EMB + e], fv, q[e]);
    }
  }
  const float* kvb = kvbuf + (size_t)b * Nn * 128;
  float sc[36];
#pragma unroll
  for (int i = 0; i < 36; ++i) sc[i] = 0.f;
#pragma unroll
  for (int widx = 0; widx < 9; ++widx) {
    const int di = widx / 3 - 1, dj = widx % 3 - 1;
    const int hh = h + di, ww = w + dj;
    if (hh < 0 || hh >= Hh || ww < 0 || ww >= Ww) continue;
    const float4* kn = (const float4*)(kvb + (size_t)(hh * Ww + ww) * 128);
#pragma unroll
    for (int e4 = 0; e4 < 16; ++e4) {
      const float4 kk = kn[e4];
      const float ka[4] = {kk.x, kk.y, kk.z, kk.w};
#pragma unroll
      for (int j = 0; j < 4; ++j) {
        const int f = (e4 * 4 + j) * 9 + widx;
        const int w2 = f >> 6, e2 = f & 63;
        sc[(e2 >> 4) * 9 + w2] = fmaf(q[e2], ka[j], sc[(e2 >> 4) * 9 + w2]);
      }
    }
  }
  float probs[36];
#pragma unroll
  for (int hdx = 0; hdx < 4; ++hdx) {
    float m = sc[hdx * 9];
#pragma unroll
    for (int w2 = 1; w2 < 9; ++w2) m = fmaxf(m, sc[hdx * 9 + w2]);
    float s = 0.f;
#pragma unroll
    for (int w2 = 0; w2 < 9; ++w2) {
      const float ev = __expf(sc[hdx * 9 + w2] - m);
      probs[hdx * 9 + w2] = ev;
      s += ev;
    }
    const float inv = 1.f / s;
#pragma unroll
    for (int w2 = 0; w2 < 9; ++w2) probs[hdx * 9 + w2] *= inv;
  }
  float ctx[EMB];
#pragma unroll
  for (int e = 0; e < EMB; ++e) ctx[e] = 0.f;
#pragma unroll
  for (int widx = 0; widx < 9; ++widx) {
    const int di = widx / 3 - 1, dj = widx % 3 - 1;
    const int hh = h + di, ww = w + dj;
    if (hh < 0 || hh >= Hh || ww < 0 || ww >= Ww) continue;
    const float4* vn = (const float4*)(kvb + (size_t)(hh * Ww + ww) * 128 + 64);
#pragma unroll
    for (int e4 = 0; e4 < 16; ++e4) {
      const float4 vv = vn[e4];
      const float va[4] = {vv.x, vv.y, vv.z, vv.w};
#pragma unroll
      for (int j = 0; j < 4; ++j) {
        const int f = (e4 * 4 + j) * 9 + widx;
        const int w2 = f >> 6, e2 = f & 63;
        ctx[e2] = fmaf(probs[(e2 >> 4) * 9 + w2], va[j], ctx[e2]);
      }
    }
  }
  const bool zero = (disp[(size_t)b * Nn + n] >= 2.0f);
  float* dout = delta + (size_t)b * CATT * Nn + n;
#pragma unroll
  for (int a = 0; a < CATT; ++a) {
    float s = 0.f;
#pragma unroll
    for (int e = 0; e < EMB; ++e) s = fmaf(Wo[a * EMB + e], ctx[e], s);
    dout[(size_t)a * Nn] = zero ? 0.f : s;
  }
}

// final add (old path only; new path fuses this into attn_fused_k)
__global__ __launch_bounds__(256) void add_k(const float* __restrict__ av,
                                             const float* __restrict__ delta,
                                             float* __restrict__ out) {
  const unsigned i4 = blockIdx.x * 256u + threadIdx.x;
  const unsigned n4 = i4 & 8191u;
  const unsigned t2 = i4 >> 13;
  const unsigned bc = t2 / 48u;
  const float4 a  = ((const float4*)av)[i4];
  const float4 dl = ((const float4*)delta)[(size_t)bc * 8192u + n4];
  ((float4*)out)[i4] = make_float4(a.x + dl.x, a.y + dl.y, a.z + dl.z, a.w + dl.w);
}

// ===========================================================================
extern "C" void kernel_launch(void* const* d_in, const int* in_sizes, int n_in,
                              void* d_out, int out_size, void* d_ws, size_t ws_size,
                              hipStream_t stream) {
  const float* attn_vol = (const float*)d_in[0];
  const float* feat     = (const float*)d_in[1];
  const float* disp     = (const float*)d_in[2];
  const float* Wq       = (const float*)d_in[3];
  const float* Wk       = (const float*)d_in[4];
  const float* Wv       = (const float*)d_in[5];
  const float* Wo       = (const float*)d_in[6];
  float* out            = (float*)d_out;
  float* ws             = (float*)d_ws;
  const int nf4 = out_size / 4;

  if (ws_size >= NEED_BYTES) {
    float* kvq = ws + WS_KVQ;
    float* wt  = ws + WS_WT;
    float* wot = ws + WS_WOT;
    hipLaunchKernelGGL(prep_new_k, dim3(512), dim3(256), 0, stream,
                       Wq, Wk, Wv, Wo, wt, wot, kvq);
    hipLaunchKernelGGL(qkv_new_k, dim3(Nn / 64, Bc), dim3(256), 0, stream,
                       feat, wt, kvq);
    hipLaunchKernelGGL(attn_fused_k, dim3(Nn / 64, Bc), dim3(256), 0, stream,
                       kvq, wot, disp, attn_vol, out);
  } else {
    float* kv    = ws + OWS_KV;
    float* delta = ws + OWS_DELTA;
    float* wtkv  = ws + OWS_WTKV;
    float* wtq   = ws + OWS_WTQ;
    hipLaunchKernelGGL(prep_weights_k, dim3(40), dim3(256), 0, stream,
                       Wq, Wk, Wv, wtkv, wtq);
    hipLaunchKernelGGL(qkv_k, dim3(Nn / 64, Bc), dim3(256), 0, stream,
                       feat, wtkv, kv);
    hipLaunchKernelGGL(attn_k, dim3(Nn / 256, Bc), dim3(256), 0, stream,
                       feat, kv, wtq, Wo, disp, delta);
    hipLaunchKernelGGL(add_k, dim3(nf4 / 256), dim3(256), 0, stream,
                       attn_vol, delta, out);
  }
}

// Round 5
// 441.950 us; speedup vs baseline: 1.1093x; 1.0967x over previous
//
#include <hip/hip_runtime.h>
#include <math.h>

namespace {
constexpr int Bc   = 4;
constexpr int CATT = 8;
constexpr int Dd   = 48;
constexpr int Hh   = 128;
constexpr int Ww   = 256;
constexpr int CF   = 80;
constexpr int EMB  = 64;
constexpr int Nn   = Hh * Ww;            // 32768
constexpr float SCALE = 0.25f;

// native vector type: required for __builtin_nontemporal_* (HIP_vector_type
// struct pointers are rejected by the builtin)
typedef float f4v __attribute__((ext_vector_type(4)));

// ---- padded-plane layout ----
constexpr int ROWP  = 264;               // 4 left pad + 256 + 4 right pad
constexpr int PLANE = 130 * ROWP;        // 34320 floats per plane (1 halo row top/bot)
constexpr size_t WS_KVQ   = 0;                                    // 4*192*PLANE
constexpr size_t WS_WT    = (size_t)Bc * 192 * PLANE;             // + 80*192
constexpr size_t WS_WOT   = WS_WT + (size_t)CF * 192;             // + 512
constexpr size_t WS_END   = WS_WOT + 512;
constexpr size_t NEED_BYTES = WS_END * 4;

// ---- old (fallback) layout ----
constexpr size_t OWS_KV    = 0;                                   // B*N*128
constexpr size_t OWS_DELTA = (size_t)Bc * Nn * 128;
constexpr size_t OWS_WTKV  = OWS_DELTA + (size_t)Bc * CATT * Nn;
constexpr size_t OWS_WTQ   = OWS_WTKV + (size_t)CF * 128;
}  // namespace

// ===========================================================================
// NEW PATH
// ===========================================================================

// prep: wt[c][192] (Q prescaled | K | V), Wot[e][8] = Wo[a][e].
// Halo zeroing: float4 writes, K/V planes only (Q halo is never read).
__global__ void prep_new_k(const float* __restrict__ Wq,
                           const float* __restrict__ Wk,
                           const float* __restrict__ Wv,
                           const float* __restrict__ Wo,
                           float* __restrict__ wt,
                           float* __restrict__ wot,
                           float* __restrict__ kvq) {
  const int t = blockIdx.x * blockDim.x + threadIdx.x;
  const int stride = gridDim.x * blockDim.x;
  for (int i = t; i < CF * 192; i += stride) {
    const int c = i / 192, o = i % 192;
    float v;
    if (o < 64)       v = Wq[o * CF + c] * SCALE;
    else if (o < 128) v = Wk[(o - 64) * CF + c];
    else              v = Wv[(o - 128) * CF + c];
    wt[i] = v;
  }
  for (int i = t; i < 512; i += stride) {
    const int e = i >> 3, a = i & 7;
    wot[i] = Wo[a * EMB + e];
  }
  // halo per plane as float4: row0 = 66, row129 = 66, rows 1..128 x {cols 0..3,
  // 260..263} = 256  -> 388 float4 per plane; planes 64..191 (K,V) only.
  constexpr int HF4 = 388;
  const float4 z4 = make_float4(0.f, 0.f, 0.f, 0.f);
  for (int i = t; i < Bc * 128 * HF4; i += stride) {
    const int f4 = i % HF4;
    const int pl = i / HF4;
    const size_t base = ((size_t)(pl / 128) * 192 + 64 + (pl % 128)) * PLANE;
    int row, col4;
    if (f4 < 66)        { row = 0;   col4 = f4 * 4; }
    else if (f4 < 132)  { row = 129; col4 = (f4 - 66) * 4; }
    else {
      const int rr = f4 - 132;
      row = (rr >> 1) + 1;
      col4 = (rr & 1) ? 260 : 0;
    }
    *(float4*)&kvq[base + (size_t)row * ROWP + col4] = z4;
  }
}

// QKV projection into padded planes. Block=256, 64-pixel row chunk.
// Thread: 12 outputs x 4 pixels. wt is staged through LDS in 16-channel
// chunks (61 KB total footprint thrashes the 32 KB L1 when read from global
// in the hot loop -> was latency-bound at VALUBusy 30%).
__global__ __launch_bounds__(256) void qkv_new_k(const float* __restrict__ feat,
                                                 const float* __restrict__ wt,
                                                 float* __restrict__ kvq) {
  __shared__ float lf[CF][64];        // 20 KB
  __shared__ float lw[16][192];       // 12 KB weight chunk
  const int b  = blockIdx.y;
  const int n0 = blockIdx.x * 64;
  const int t  = threadIdx.x;

  const float* fb = feat + (size_t)b * CF * Nn + n0;
  for (int i = t; i < CF * 64; i += 256) {
    const int c = i >> 6, p = i & 63;
    lf[c][p] = fb[(size_t)c * Nn + p];
  }

  const int og = t >> 4;          // 16 groups of 12 outputs
  const int p4 = (t & 15) * 4;

  float acc[12][4];
#pragma unroll
  for (int o = 0; o < 12; ++o)
#pragma unroll
    for (int j = 0; j < 4; ++j) acc[o][j] = 0.f;

  for (int c0 = 0; c0 < CF; c0 += 16) {
    __syncthreads();               // first iter: covers lf staging too
    // stage 16x192 weight chunk: 768 float4, 3 per thread
    for (int i = t; i < 768; i += 256)
      ((float4*)lw)[i] = ((const float4*)(wt + c0 * 192))[i];
    __syncthreads();
#pragma unroll
    for (int cc = 0; cc < 16; ++cc) {
      const float4 fv = *(const float4*)&lf[c0 + cc][p4];
      const float fa[4] = {fv.x, fv.y, fv.z, fv.w};
      const float4 w0 = *(const float4*)&lw[cc][og * 12];
      const float4 w1 = *(const float4*)&lw[cc][og * 12 + 4];
      const float4 w2 = *(const float4*)&lw[cc][og * 12 + 8];
      const float wv12[12] = {w0.x, w0.y, w0.z, w0.w, w1.x, w1.y, w1.z, w1.w,
                              w2.x, w2.y, w2.z, w2.w};
#pragma unroll
      for (int o = 0; o < 12; ++o)
#pragma unroll
        for (int j = 0; j < 4; ++j) acc[o][j] = fmaf(wv12[o], fa[j], acc[o][j]);
    }
  }

  const int h = n0 >> 8, w0c = n0 & 255;
  float* bbase = kvq + (size_t)b * 192 * PLANE;
  const int rowoff = (h + 1) * ROWP + (w0c + 4) + p4;
#pragma unroll
  for (int o = 0; o < 12; ++o) {
    const int oo = og * 12 + o;
    *(float4*)&bbase[(size_t)oo * PLANE + rowoff] =
        make_float4(acc[o][0], acc[o][1], acc[o][2], acc[o][3]);
  }
}

// attention core for one head (wave-uniform HD -> compile-time offsets)
template <int HD>
__device__ __forceinline__ void attn_core(const float* __restrict__ kb, int coff,
                                          const float* __restrict__ lwot,
                                          float* __restrict__ part) {
  float q16[16];
#pragma unroll
  for (int i = 0; i < 16; ++i)
    q16[i] = kb[(size_t)(HD * 16 + i) * PLANE + coff];

  float sc[9];
#pragma unroll
  for (int w2 = 0; w2 < 9; ++w2) {
    float s = 0.f;
#pragma unroll
    for (int i = 0; i < 16; ++i) {
      const int f = w2 * 64 + HD * 16 + i;       // compile-time after unroll
      const int e = f / 9, widx = f % 9;
      const int D = (widx / 3 - 1) * ROWP + (widx % 3 - 1);
      s = fmaf(q16[i], kb[(size_t)(64 + e) * PLANE + coff + D], s);
    }
    sc[w2] = s;
  }

  float m = sc[0];
#pragma unroll
  for (int w2 = 1; w2 < 9; ++w2) m = fmaxf(m, sc[w2]);
  float probs[9], ssum = 0.f;
#pragma unroll
  for (int w2 = 0; w2 < 9; ++w2) {
    probs[w2] = __expf(sc[w2] - m);
    ssum += probs[w2];
  }
  const float inv = 1.f / ssum;
#pragma unroll
  for (int w2 = 0; w2 < 9; ++w2) probs[w2] *= inv;

  float ctx[16];
#pragma unroll
  for (int i = 0; i < 16; ++i) {
    float c = 0.f;
#pragma unroll
    for (int w2 = 0; w2 < 9; ++w2) {
      const int f = w2 * 64 + HD * 16 + i;
      const int e = f / 9, widx = f % 9;
      const int D = (widx / 3 - 1) * ROWP + (widx % 3 - 1);
      c = fmaf(probs[w2], kb[(size_t)(128 + e) * PLANE + coff + D], c);
    }
    ctx[i] = c;
  }

#pragma unroll
  for (int a = 0; a < 8; ++a) {
    float p = 0.f;
#pragma unroll
    for (int i = 0; i < 16; ++i)
      p = fmaf(lwot[(HD * 16 + i) * 8 + a], ctx[i], p);
    part[a] = p;
  }
}

// Fused attention + D-broadcast residual add.
// Block=256 (4 waves), wave = head, lanes = 64 consecutive pixels of one row.
// Per-pixel sums go to LDS (lsv), then the whole block streams
// out = attn_vol + delta as float4 (4x fewer VMEM instrs than scalar).
__global__ __launch_bounds__(256) void attn_fused_k(const float* __restrict__ kvq,
                                                    const float* __restrict__ wot,
                                                    const float* __restrict__ disp,
                                                    const float* __restrict__ av,
                                                    float* __restrict__ out) {
  __shared__ float lwot[512];
  __shared__ float lpart[4 * 576];   // [hd][px*9 + a], stride 9 kills bank conflicts
  __shared__ float lsv[64][9];       // summed+masked delta per (px, a); pad to 9
  const int b = blockIdx.y;
  const int t = threadIdx.x;
  for (int i = t; i < 512; i += 256) lwot[i] = wot[i];
  __syncthreads();

  const int hd = t >> 6, lane = t & 63;
  const int n = blockIdx.x * 64 + lane;
  const int h = n >> 8, w = n & 255;
  const int coff = (h + 1) * ROWP + (w + 4);
  const float* kb = kvq + (size_t)b * 192 * PLANE;

  float part[8];
  switch (hd) {
    case 0: attn_core<0>(kb, coff, lwot, part); break;
    case 1: attn_core<1>(kb, coff, lwot, part); break;
    case 2: attn_core<2>(kb, coff, lwot, part); break;
    default: attn_core<3>(kb, coff, lwot, part); break;
  }
#pragma unroll
  for (int a = 0; a < 8; ++a) lpart[hd * 576 + lane * 9 + a] = part[a];
  __syncthreads();

  {
    const int px = t & 63, ag = t >> 6;
    const int nn = blockIdx.x * 64 + px;
    const bool zero = disp[(size_t)b * Nn + nn] >= 2.0f;
#pragma unroll
    for (int k = 0; k < 2; ++k) {
      const int a = ag * 2 + k;
      const float s = lpart[0 * 576 + px * 9 + a] + lpart[1 * 576 + px * 9 + a] +
                      lpart[2 * 576 + px * 9 + a] + lpart[3 * 576 + px * 9 + a];
      lsv[px][a] = zero ? 0.f : s;
    }
  }
  __syncthreads();

  // stream phase: 256 threads = 8 a x 2 d-halves x 16 px-quads
  const int a2  = t >> 5;
  const int dh  = (t >> 4) & 1;
  const int px4 = (t & 15) * 4;
  f4v sv4;
  sv4.x = lsv[px4 + 0][a2]; sv4.y = lsv[px4 + 1][a2];
  sv4.z = lsv[px4 + 2][a2]; sv4.w = lsv[px4 + 3][a2];
  const size_t nn0 = (size_t)blockIdx.x * 64 + px4;
  const size_t base = (((size_t)(b * CATT + a2) * Dd) + dh * 24) * Nn + nn0;
  const f4v* ab = (const f4v*)(av + base);
  f4v* ob = (f4v*)(out + base);
  constexpr size_t STR = Nn / 4;     // f4v stride between d planes
#pragma unroll
  for (int d0 = 0; d0 < 24; d0 += 6) {
    f4v v[6];
#pragma unroll
    for (int j = 0; j < 6; ++j)
      v[j] = __builtin_nontemporal_load(ab + (size_t)(d0 + j) * STR);
#pragma unroll
    for (int j = 0; j < 6; ++j) {
      v[j] += sv4;
      __builtin_nontemporal_store(v[j], ob + (size_t)(d0 + j) * STR);
    }
  }
}

// ===========================================================================
// OLD PATH (fallback if ws too small) — identical to the passing R2 kernels
// ===========================================================================
__global__ void prep_weights_k(const float* __restrict__ Wq,
                               const float* __restrict__ Wk,
                               const float* __restrict__ Wv,
                               float* __restrict__ wtkv,
                               float* __restrict__ wtq) {
  const int t = blockIdx.x * blockDim.x + threadIdx.x;
  const int stride = gridDim.x * blockDim.x;
  for (int i = t; i < CF * 128; i += stride) {
    const int c = i >> 7, o = i & 127;
    wtkv[i] = (o < 64) ? Wk[o * CF + c] : Wv[(o - 64) * CF + c];
  }
  for (int i = t; i < CF * 64; i += stride) {
    const int c = i >> 6, e = i & 63;
    wtq[i] = Wq[e * CF + c] * SCALE;
  }
}

__global__ __launch_bounds__(256) void qkv_k(const float* __restrict__ feat,
                                             const float* __restrict__ wtkv,
                                             float* __restrict__ kv) {
  __shared__ float lf[CF][64];
  const int b  = blockIdx.y;
  const int n0 = blockIdx.x * 64;
  const int t  = threadIdx.x;
  const float* fb = feat + (size_t)b * CF * Nn + n0;
  for (int i = t; i < CF * 64; i += 256) {
    const int c = i >> 6, p = i & 63;
    lf[c][p] = fb[(size_t)c * Nn + p];
  }
  __syncthreads();
  const int og = t >> 4;
  const int p4 = (t & 15) * 4;
  float acc[8][4];
#pragma unroll
  for (int o = 0; o < 8; ++o)
#pragma unroll
    for (int j = 0; j < 4; ++j) acc[o][j] = 0.f;
  for (int c = 0; c < CF; ++c) {
    const float4 fv = *(const float4*)&lf[c][p4];
    const float fa[4] = {fv.x, fv.y, fv.z, fv.w};
    const float4 wa = *(const float4*)&wtkv[c * 128 + og * 8];
    const float4 wb = *(const float4*)&wtkv[c * 128 + og * 8 + 4];
    const float wv8[8] = {wa.x, wa.y, wa.z, wa.w, wb.x, wb.y, wb.z, wb.w};
#pragma unroll
    for (int o = 0; o < 8; ++o)
#pragma unroll
      for (int j = 0; j < 4; ++j) acc[o][j] = fmaf(wv8[o], fa[j], acc[o][j]);
  }
  float* outb = kv + ((size_t)b * Nn + n0) * 128;
#pragma unroll
  for (int j = 0; j < 4; ++j) {
    const int p = p4 + j;
    *(float4*)&outb[(size_t)p * 128 + og * 8] =
        make_float4(acc[0][j], acc[1][j], acc[2][j], acc[3][j]);
    *(float4*)&outb[(size_t)p * 128 + og * 8 + 4] =
        make_float4(acc[4][j], acc[5][j], acc[6][j], acc[7][j]);
  }
}

__global__ __launch_bounds__(256) void attn_k(const float* __restrict__ feat,
                                              const float* __restrict__ kvbuf,
                                              const float* __restrict__ wtq,
                                              const float* __restrict__ Wo,
                                              const float* __restrict__ disp,
                                              float* __restrict__ delta) {
  const int b = blockIdx.y;
  const int n = blockIdx.x * 256 + threadIdx.x;
  const int h = n >> 8;
  const int w = n & 255;
  float q[EMB];
#pragma unroll
  for (int e = 0; e < EMB; ++e) q[e] = 0.f;
  {
    const float* fb = feat + (size_t)b * CF * Nn + n;
    for (int c = 0; c < CF; ++c) {
      const float fv = fb[(size_t)c * Nn];
#pragma unroll
      for (int e = 0; e < EMB; ++e) q[e] = fmaf(wtq[c * EMB + e], fv, q[e]);
    }
  }
  const float* kvb = kvbuf + (size_t)b * Nn * 128;
  float sc[36];
#pragma unroll
  for (int i = 0; i < 36; ++i) sc[i] = 0.f;
#pragma unroll
  for (int widx = 0; widx < 9; ++widx) {
    const int di = widx / 3 - 1, dj = widx % 3 - 1;
    const int hh = h + di, ww = w + dj;
    if (hh < 0 || hh >= Hh || ww < 0 || ww >= Ww) continue;
    const float4* kn = (const float4*)(kvb + (size_t)(hh * Ww + ww) * 128);
#pragma unroll
    for (int e4 = 0; e4 < 16; ++e4) {
      const float4 kk = kn[e4];
      const float ka[4] = {kk.x, kk.y, kk.z, kk.w};
#pragma unroll
      for (int j = 0; j < 4; ++j) {
        const int f = (e4 * 4 + j) * 9 + widx;
        const int w2 = f >> 6, e2 = f & 63;
        sc[(e2 >> 4) * 9 + w2] = fmaf(q[e2], ka[j], sc[(e2 >> 4) * 9 + w2]);
      }
    }
  }
  float probs[36];
#pragma unroll
  for (int hdx = 0; hdx < 4; ++hdx) {
    float m = sc[hdx * 9];
#pragma unroll
    for (int w2 = 1; w2 < 9; ++w2) m = fmaxf(m, sc[hdx * 9 + w2]);
    float s = 0.f;
#pragma unroll
    for (int w2 = 0; w2 < 9; ++w2) {
      const float ev = __expf(sc[hdx * 9 + w2] - m);
      probs[hdx * 9 + w2] = ev;
      s += ev;
    }
    const float inv = 1.f / s;
#pragma unroll
    for (int w2 = 0; w2 < 9; ++w2) probs[hdx * 9 + w2] *= inv;
  }
  float ctx[EMB];
#pragma unroll
  for (int e = 0; e < EMB; ++e) ctx[e] = 0.f;
#pragma unroll
  for (int widx = 0; widx < 9; ++widx) {
    const int di = widx / 3 - 1, dj = widx % 3 - 1;
    const int hh = h + di, ww = w + dj;
    if (hh < 0 || hh >= Hh || ww < 0 || ww >= Ww) continue;
    const float4* vn = (const float4*)(kvb + (size_t)(hh * Ww + ww) * 128 + 64);
#pragma unroll
    for (int e4 = 0; e4 < 16; ++e4) {
      const float4 vv = vn[e4];
      const float va[4] = {vv.x, vv.y, vv.z, vv.w};
#pragma unroll
      for (int j = 0; j < 4; ++j) {
        const int f = (e4 * 4 + j) * 9 + widx;
        const int w2 = f >> 6, e2 = f & 63;
        ctx[e2] = fmaf(probs[(e2 >> 4) * 9 + w2], va[j], ctx[e2]);
      }
    }
  }
  const bool zero = (disp[(size_t)b * Nn + n] >= 2.0f);
  float* dout = delta + (size_t)b * CATT * Nn + n;
#pragma unroll
  for (int a = 0; a < CATT; ++a) {
    float s = 0.f;
#pragma unroll
    for (int e = 0; e < EMB; ++e) s = fmaf(Wo[a * EMB + e], ctx[e], s);
    dout[(size_t)a * Nn] = zero ? 0.f : s;
  }
}

// final add (old path only; new path fuses this into attn_fused_k)
__global__ __launch_bounds__(256) void add_k(const float* __restrict__ av,
                                             const float* __restrict__ delta,
                                             float* __restrict__ out) {
  const unsigned i4 = blockIdx.x * 256u + threadIdx.x;
  const unsigned n4 = i4 & 8191u;
  const unsigned t2 = i4 >> 13;
  const unsigned bc = t2 / 48u;
  const float4 a  = ((const float4*)av)[i4];
  const float4 dl = ((const float4*)delta)[(size_t)bc * 8192u + n4];
  ((float4*)out)[i4] = make_float4(a.x + dl.x, a.y + dl.y, a.z + dl.z, a.w + dl.w);
}

// ===========================================================================
extern "C" void kernel_launch(void* const* d_in, const int* in_sizes, int n_in,
                              void* d_out, int out_size, void* d_ws, size_t ws_size,
                              hipStream_t stream) {
  const float* attn_vol = (const float*)d_in[0];
  const float* feat     = (const float*)d_in[1];
  const float* disp     = (const float*)d_in[2];
  const float* Wq       = (const float*)d_in[3];
  const float* Wk       = (const float*)d_in[4];
  const float* Wv       = (const float*)d_in[5];
  const float* Wo       = (const float*)d_in[6];
  float* out            = (float*)d_out;
  float* ws             = (float*)d_ws;
  const int nf4 = out_size / 4;

  if (ws_size >= NEED_BYTES) {
    float* kvq = ws + WS_KVQ;
    float* wt  = ws + WS_WT;
    float* wot = ws + WS_WOT;
    hipLaunchKernelGGL(prep_new_k, dim3(512), dim3(256), 0, stream,
                       Wq, Wk, Wv, Wo, wt, wot, kvq);
    hipLaunchKernelGGL(qkv_new_k, dim3(Nn / 64, Bc), dim3(256), 0, stream,
                       feat, wt, kvq);
    hipLaunchKernelGGL(attn_fused_k, dim3(Nn / 64, Bc), dim3(256), 0, stream,
                       kvq, wot, disp, attn_vol, out);
  } else {
    float* kv    = ws + OWS_KV;
    float* delta = ws + OWS_DELTA;
    float* wtkv  = ws + OWS_WTKV;
    float* wtq   = ws + OWS_WTQ;
    hipLaunchKernelGGL(prep_weights_k, dim3(40), dim3(256), 0, stream,
                       Wq, Wk, Wv, wtkv, wtq);
    hipLaunchKernelGGL(qkv_k, dim3(Nn / 64, Bc), dim3(256), 0, stream,
                       feat, wtkv, kv);
    hipLaunchKernelGGL(attn_k, dim3(Nn / 256, Bc), dim3(256), 0, stream,
                       feat, kv, wtq, Wo, disp, delta);
    hipLaunchKernelGGL(add_k, dim3(nf4 / 256), dim3(256), 0, stream,
                       attn_vol, delta, out);
  }
}

// Round 6
// 431.954 us; speedup vs baseline: 1.1350x; 1.0231x over previous
//
#include <hip/hip_runtime.h>
#include <math.h>

namespace {
constexpr int Bc   = 4;
constexpr int CATT = 8;
constexpr int Dd   = 48;
constexpr int Hh   = 128;
constexpr int Ww   = 256;
constexpr int CF   = 80;
constexpr int EMB  = 64;
constexpr int Nn   = Hh * Ww;            // 32768
constexpr float SCALE = 0.25f;

// native vector type: required for __builtin_nontemporal_* (HIP_vector_type
// struct pointers are rejected by the builtin)
typedef float f4v __attribute__((ext_vector_type(4)));

// ---- padded-plane layout ----
constexpr int ROWP  = 264;               // 4 left pad + 256 + 4 right pad
constexpr int PLANE = 130 * ROWP;        // 34320 floats per plane (1 halo row top/bot)
constexpr size_t WS_KVQ   = 0;                                    // 4*192*PLANE
constexpr size_t WS_WT    = (size_t)Bc * 192 * PLANE;             // + 80*192
constexpr size_t WS_WOT   = WS_WT + (size_t)CF * 192;             // + 512
constexpr size_t WS_END   = WS_WOT + 512;
constexpr size_t NEED_BYTES = WS_END * 4;

// ---- old (fallback) layout ----
constexpr size_t OWS_KV    = 0;                                   // B*N*128
constexpr size_t OWS_DELTA = (size_t)Bc * Nn * 128;
constexpr size_t OWS_WTKV  = OWS_DELTA + (size_t)Bc * CATT * Nn;
constexpr size_t OWS_WTQ   = OWS_WTKV + (size_t)CF * 128;

// XCD-aware chunk swizzle: 512 row-chunks per image, 8 XCDs. Linear dispatch
// round-robins blocks across XCDs, so adjacent chunks (which share K/V halo
// rows) land on different XCDs' L2s. Remap so XCD k owns a contiguous 16-row
// band (3 MB kvq working set < 4 MB L2). Bijective since 512 = 8*64.
__device__ __forceinline__ int swz_chunk(int bx) {
  return ((bx & 7) << 6) | (bx >> 3);
}
}  // namespace

// ===========================================================================
// NEW PATH
// ===========================================================================

// prep: wt[c][192] (Q prescaled | K | V), Wot[e][8] = Wo[a][e].
// Halo zeroing: float4 writes, K/V planes only (Q halo is never read).
__global__ void prep_new_k(const float* __restrict__ Wq,
                           const float* __restrict__ Wk,
                           const float* __restrict__ Wv,
                           const float* __restrict__ Wo,
                           float* __restrict__ wt,
                           float* __restrict__ wot,
                           float* __restrict__ kvq) {
  const int t = blockIdx.x * blockDim.x + threadIdx.x;
  const int stride = gridDim.x * blockDim.x;
  for (int i = t; i < CF * 192; i += stride) {
    const int c = i / 192, o = i % 192;
    float v;
    if (o < 64)       v = Wq[o * CF + c] * SCALE;
    else if (o < 128) v = Wk[(o - 64) * CF + c];
    else              v = Wv[(o - 128) * CF + c];
    wt[i] = v;
  }
  for (int i = t; i < 512; i += stride) {
    const int e = i >> 3, a = i & 7;
    wot[i] = Wo[a * EMB + e];
  }
  // halo per plane as float4: row0 = 66, row129 = 66, rows 1..128 x {cols 0..3,
  // 260..263} = 256  -> 388 float4 per plane; planes 64..191 (K,V) only.
  constexpr int HF4 = 388;
  const float4 z4 = make_float4(0.f, 0.f, 0.f, 0.f);
  for (int i = t; i < Bc * 128 * HF4; i += stride) {
    const int f4 = i % HF4;
    const int pl = i / HF4;
    const size_t base = ((size_t)(pl / 128) * 192 + 64 + (pl % 128)) * PLANE;
    int row, col4;
    if (f4 < 66)        { row = 0;   col4 = f4 * 4; }
    else if (f4 < 132)  { row = 129; col4 = (f4 - 66) * 4; }
    else {
      const int rr = f4 - 132;
      row = (rr >> 1) + 1;
      col4 = (rr & 1) ? 260 : 0;
    }
    *(float4*)&kvq[base + (size_t)row * ROWP + col4] = z4;
  }
}

// QKV projection into padded planes. Block=256, 64-pixel row chunk.
// Thread: 12 outputs x 4 pixels. wt is staged through LDS in 16-channel
// chunks (61 KB total footprint thrashes the 32 KB L1 when read from global
// in the hot loop -> was latency-bound at VALUBusy 30%).
__global__ __launch_bounds__(256) void qkv_new_k(const float* __restrict__ feat,
                                                 const float* __restrict__ wt,
                                                 float* __restrict__ kvq) {
  __shared__ float lf[CF][64];        // 20 KB
  __shared__ float lw[16][192];       // 12 KB weight chunk
  const int b  = blockIdx.y;
  const int cx = swz_chunk(blockIdx.x);
  const int n0 = cx * 64;
  const int t  = threadIdx.x;

  const float* fb = feat + (size_t)b * CF * Nn + n0;
  for (int i = t; i < CF * 64; i += 256) {
    const int c = i >> 6, p = i & 63;
    lf[c][p] = fb[(size_t)c * Nn + p];
  }

  const int og = t >> 4;          // 16 groups of 12 outputs
  const int p4 = (t & 15) * 4;

  float acc[12][4];
#pragma unroll
  for (int o = 0; o < 12; ++o)
#pragma unroll
    for (int j = 0; j < 4; ++j) acc[o][j] = 0.f;

  for (int c0 = 0; c0 < CF; c0 += 16) {
    __syncthreads();               // first iter: covers lf staging too
    // stage 16x192 weight chunk: 768 float4, 3 per thread
    for (int i = t; i < 768; i += 256)
      ((float4*)lw)[i] = ((const float4*)(wt + c0 * 192))[i];
    __syncthreads();
#pragma unroll
    for (int cc = 0; cc < 16; ++cc) {
      const float4 fv = *(const float4*)&lf[c0 + cc][p4];
      const float fa[4] = {fv.x, fv.y, fv.z, fv.w};
      const float4 w0 = *(const float4*)&lw[cc][og * 12];
      const float4 w1 = *(const float4*)&lw[cc][og * 12 + 4];
      const float4 w2 = *(const float4*)&lw[cc][og * 12 + 8];
      const float wv12[12] = {w0.x, w0.y, w0.z, w0.w, w1.x, w1.y, w1.z, w1.w,
                              w2.x, w2.y, w2.z, w2.w};
#pragma unroll
      for (int o = 0; o < 12; ++o)
#pragma unroll
        for (int j = 0; j < 4; ++j) acc[o][j] = fmaf(wv12[o], fa[j], acc[o][j]);
    }
  }

  const int h = n0 >> 8, w0c = n0 & 255;
  float* bbase = kvq + (size_t)b * 192 * PLANE;
  const int rowoff = (h + 1) * ROWP + (w0c + 4) + p4;
#pragma unroll
  for (int o = 0; o < 12; ++o) {
    const int oo = og * 12 + o;
    *(float4*)&bbase[(size_t)oo * PLANE + rowoff] =
        make_float4(acc[o][0], acc[o][1], acc[o][2], acc[o][3]);
  }
}

// attention core for one head (wave-uniform HD -> compile-time offsets)
template <int HD>
__device__ __forceinline__ void attn_core(const float* __restrict__ kb, int coff,
                                          const float* __restrict__ lwot,
                                          float* __restrict__ part) {
  float q16[16];
#pragma unroll
  for (int i = 0; i < 16; ++i)
    q16[i] = kb[(size_t)(HD * 16 + i) * PLANE + coff];

  float sc[9];
#pragma unroll
  for (int w2 = 0; w2 < 9; ++w2) {
    float s = 0.f;
#pragma unroll
    for (int i = 0; i < 16; ++i) {
      const int f = w2 * 64 + HD * 16 + i;       // compile-time after unroll
      const int e = f / 9, widx = f % 9;
      const int D = (widx / 3 - 1) * ROWP + (widx % 3 - 1);
      s = fmaf(q16[i], kb[(size_t)(64 + e) * PLANE + coff + D], s);
    }
    sc[w2] = s;
  }

  float m = sc[0];
#pragma unroll
  for (int w2 = 1; w2 < 9; ++w2) m = fmaxf(m, sc[w2]);
  float probs[9], ssum = 0.f;
#pragma unroll
  for (int w2 = 0; w2 < 9; ++w2) {
    probs[w2] = __expf(sc[w2] - m);
    ssum += probs[w2];
  }
  const float inv = 1.f / ssum;
#pragma unroll
  for (int w2 = 0; w2 < 9; ++w2) probs[w2] *= inv;

  float ctx[16];
#pragma unroll
  for (int i = 0; i < 16; ++i) {
    float c = 0.f;
#pragma unroll
    for (int w2 = 0; w2 < 9; ++w2) {
      const int f = w2 * 64 + HD * 16 + i;
      const int e = f / 9, widx = f % 9;
      const int D = (widx / 3 - 1) * ROWP + (widx % 3 - 1);
      c = fmaf(probs[w2], kb[(size_t)(128 + e) * PLANE + coff + D], c);
    }
    ctx[i] = c;
  }

#pragma unroll
  for (int a = 0; a < 8; ++a) {
    float p = 0.f;
#pragma unroll
    for (int i = 0; i < 16; ++i)
      p = fmaf(lwot[(HD * 16 + i) * 8 + a], ctx[i], p);
    part[a] = p;
  }
}

// Fused attention + D-broadcast residual add.
// Block=256 (4 waves), wave = head, lanes = 64 consecutive pixels of one row.
// Per-pixel sums go to LDS (lsv), then the whole block streams
// out = attn_vol + delta as float4 (4x fewer VMEM instrs than scalar).
__global__ __launch_bounds__(256) void attn_fused_k(const float* __restrict__ kvq,
                                                    const float* __restrict__ wot,
                                                    const float* __restrict__ disp,
                                                    const float* __restrict__ av,
                                                    float* __restrict__ out) {
  __shared__ float lwot[512];
  __shared__ float lpart[4 * 576];   // [hd][px*9 + a], stride 9 kills bank conflicts
  __shared__ float lsv[64][9];       // summed+masked delta per (px, a); pad to 9
  const int b = blockIdx.y;
  const int cx = swz_chunk(blockIdx.x);
  const int t = threadIdx.x;
  for (int i = t; i < 512; i += 256) lwot[i] = wot[i];
  __syncthreads();

  const int hd = t >> 6, lane = t & 63;
  const int n = cx * 64 + lane;
  const int h = n >> 8, w = n & 255;
  const int coff = (h + 1) * ROWP + (w + 4);
  const float* kb = kvq + (size_t)b * 192 * PLANE;

  float part[8];
  switch (hd) {
    case 0: attn_core<0>(kb, coff, lwot, part); break;
    case 1: attn_core<1>(kb, coff, lwot, part); break;
    case 2: attn_core<2>(kb, coff, lwot, part); break;
    default: attn_core<3>(kb, coff, lwot, part); break;
  }
#pragma unroll
  for (int a = 0; a < 8; ++a) lpart[hd * 576 + lane * 9 + a] = part[a];
  __syncthreads();

  {
    const int px = t & 63, ag = t >> 6;
    const int nn = cx * 64 + px;
    const bool zero = disp[(size_t)b * Nn + nn] >= 2.0f;
#pragma unroll
    for (int k = 0; k < 2; ++k) {
      const int a = ag * 2 + k;
      const float s = lpart[0 * 576 + px * 9 + a] + lpart[1 * 576 + px * 9 + a] +
                      lpart[2 * 576 + px * 9 + a] + lpart[3 * 576 + px * 9 + a];
      lsv[px][a] = zero ? 0.f : s;
    }
  }
  __syncthreads();

  // stream phase: 256 threads = 8 a x 2 d-halves x 16 px-quads
  const int a2  = t >> 5;
  const int dh  = (t >> 4) & 1;
  const int px4 = (t & 15) * 4;
  f4v sv4;
  sv4.x = lsv[px4 + 0][a2]; sv4.y = lsv[px4 + 1][a2];
  sv4.z = lsv[px4 + 2][a2]; sv4.w = lsv[px4 + 3][a2];
  const size_t nn0 = (size_t)cx * 64 + px4;
  const size_t base = (((size_t)(b * CATT + a2) * Dd) + dh * 24) * Nn + nn0;
  const f4v* ab = (const f4v*)(av + base);
  f4v* ob = (f4v*)(out + base);
  constexpr size_t STR = Nn / 4;     // f4v stride between d planes
#pragma unroll
  for (int d0 = 0; d0 < 24; d0 += 6) {
    f4v v[6];
#pragma unroll
    for (int j = 0; j < 6; ++j)
      v[j] = __builtin_nontemporal_load(ab + (size_t)(d0 + j) * STR);
#pragma unroll
    for (int j = 0; j < 6; ++j) {
      v[j] += sv4;
      __builtin_nontemporal_store(v[j], ob + (size_t)(d0 + j) * STR);
    }
  }
}

// ===========================================================================
// OLD PATH (fallback if ws too small) — identical to the passing R2 kernels
// ===========================================================================
__global__ void prep_weights_k(const float* __restrict__ Wq,
                               const float* __restrict__ Wk,
                               const float* __restrict__ Wv,
                               float* __restrict__ wtkv,
                               float* __restrict__ wtq) {
  const int t = blockIdx.x * blockDim.x + threadIdx.x;
  const int stride = gridDim.x * blockDim.x;
  for (int i = t; i < CF * 128; i += stride) {
    const int c = i >> 7, o = i & 127;
    wtkv[i] = (o < 64) ? Wk[o * CF + c] : Wv[(o - 64) * CF + c];
  }
  for (int i = t; i < CF * 64; i += stride) {
    const int c = i >> 6, e = i & 63;
    wtq[i] = Wq[e * CF + c] * SCALE;
  }
}

__global__ __launch_bounds__(256) void qkv_k(const float* __restrict__ feat,
                                             const float* __restrict__ wtkv,
                                             float* __restrict__ kv) {
  __shared__ float lf[CF][64];
  const int b  = blockIdx.y;
  const int n0 = blockIdx.x * 64;
  const int t  = threadIdx.x;
  const float* fb = feat + (size_t)b * CF * Nn + n0;
  for (int i = t; i < CF * 64; i += 256) {
    const int c = i >> 6, p = i & 63;
    lf[c][p] = fb[(size_t)c * Nn + p];
  }
  __syncthreads();
  const int og = t >> 4;
  const int p4 = (t & 15) * 4;
  float acc[8][4];
#pragma unroll
  for (int o = 0; o < 8; ++o)
#pragma unroll
    for (int j = 0; j < 4; ++j) acc[o][j] = 0.f;
  for (int c = 0; c < CF; ++c) {
    const float4 fv = *(const float4*)&lf[c][p4];
    const float fa[4] = {fv.x, fv.y, fv.z, fv.w};
    const float4 wa = *(const float4*)&wtkv[c * 128 + og * 8];
    const float4 wb = *(const float4*)&wtkv[c * 128 + og * 8 + 4];
    const float wv8[8] = {wa.x, wa.y, wa.z, wa.w, wb.x, wb.y, wb.z, wb.w};
#pragma unroll
    for (int o = 0; o < 8; ++o)
#pragma unroll
      for (int j = 0; j < 4; ++j) acc[o][j] = fmaf(wv8[o], fa[j], acc[o][j]);
  }
  float* outb = kv + ((size_t)b * Nn + n0) * 128;
#pragma unroll
  for (int j = 0; j < 4; ++j) {
    const int p = p4 + j;
    *(float4*)&outb[(size_t)p * 128 + og * 8] =
        make_float4(acc[0][j], acc[1][j], acc[2][j], acc[3][j]);
    *(float4*)&outb[(size_t)p * 128 + og * 8 + 4] =
        make_float4(acc[4][j], acc[5][j], acc[6][j], acc[7][j]);
  }
}

__global__ __launch_bounds__(256) void attn_k(const float* __restrict__ feat,
                                              const float* __restrict__ kvbuf,
                                              const float* __restrict__ wtq,
                                              const float* __restrict__ Wo,
                                              const float* __restrict__ disp,
                                              float* __restrict__ delta) {
  const int b = blockIdx.y;
  const int n = blockIdx.x * 256 + threadIdx.x;
  const int h = n >> 8;
  const int w = n & 255;
  float q[EMB];
#pragma unroll
  for (int e = 0; e < EMB; ++e) q[e] = 0.f;
  {
    const float* fb = feat + (size_t)b * CF * Nn + n;
    for (int c = 0; c < CF; ++c) {
      const float fv = fb[(size_t)c * Nn];
#pragma unroll
      for (int e = 0; e < EMB; ++e) q[e] = fmaf(wtq[c * EMB + e], fv, q[e]);
    }
  }
  const float* kvb = kvbuf + (size_t)b * Nn * 128;
  float sc[36];
#pragma unroll
  for (int i = 0; i < 36; ++i) sc[i] = 0.f;
#pragma unroll
  for (int widx = 0; widx < 9; ++widx) {
    const int di = widx / 3 - 1, dj = widx % 3 - 1;
    const int hh = h + di, ww = w + dj;
    if (hh < 0 || hh >= Hh || ww < 0 || ww >= Ww) continue;
    const float4* kn = (const float4*)(kvb + (size_t)(hh * Ww + ww) * 128);
#pragma unroll
    for (int e4 = 0; e4 < 16; ++e4) {
      const float4 kk = kn[e4];
      const float ka[4] = {kk.x, kk.y, kk.z, kk.w};
#pragma unroll
      for (int j = 0; j < 4; ++j) {
        const int f = (e4 * 4 + j) * 9 + widx;
        const int w2 = f >> 6, e2 = f & 63;
        sc[(e2 >> 4) * 9 + w2] = fmaf(q[e2], ka[j], sc[(e2 >> 4) * 9 + w2]);
      }
    }
  }
  float probs[36];
#pragma unroll
  for (int hdx = 0; hdx < 4; ++hdx) {
    float m = sc[hdx * 9];
#pragma unroll
    for (int w2 = 1; w2 < 9; ++w2) m = fmaxf(m, sc[hdx * 9 + w2]);
    float s = 0.f;
#pragma unroll
    for (int w2 = 0; w2 < 9; ++w2) {
      const float ev = __expf(sc[hdx * 9 + w2] - m);
      probs[hdx * 9 + w2] = ev;
      s += ev;
    }
    const float inv = 1.f / s;
#pragma unroll
    for (int w2 = 0; w2 < 9; ++w2) probs[hdx * 9 + w2] *= inv;
  }
  float ctx[EMB];
#pragma unroll
  for (int e = 0; e < EMB; ++e) ctx[e] = 0.f;
#pragma unroll
  for (int widx = 0; widx < 9; ++widx) {
    const int di = widx / 3 - 1, dj = widx % 3 - 1;
    const int hh = h + di, ww = w + dj;
    if (hh < 0 || hh >= Hh || ww < 0 || ww >= Ww) continue;
    const float4* vn = (const float4*)(kvb + (size_t)(hh * Ww + ww) * 128 + 64);
#pragma unroll
    for (int e4 = 0; e4 < 16; ++e4) {
      const float4 vv = vn[e4];
      const float va[4] = {vv.x, vv.y, vv.z, vv.w};
#pragma unroll
      for (int j = 0; j < 4; ++j) {
        const int f = (e4 * 4 + j) * 9 + widx;
        const int w2 = f >> 6, e2 = f & 63;
        ctx[e2] = fmaf(probs[(e2 >> 4) * 9 + w2], va[j], ctx[e2]);
      }
    }
  }
  const bool zero = (disp[(size_t)b * Nn + n] >= 2.0f);
  float* dout = delta + (size_t)b * CATT * Nn + n;
#pragma unroll
  for (int a = 0; a < CATT; ++a) {
    float s = 0.f;
#pragma unroll
    for (int e = 0; e < EMB; ++e) s = fmaf(Wo[a * EMB + e], ctx[e], s);
    dout[(size_t)a * Nn] = zero ? 0.f : s;
  }
}

// final add (old path only; new path fuses this into attn_fused_k)
__global__ __launch_bounds__(256) void add_k(const float* __restrict__ av,
                                             const float* __restrict__ delta,
                                             float* __restrict__ out) {
  const unsigned i4 = blockIdx.x * 256u + threadIdx.x;
  const unsigned n4 = i4 & 8191u;
  const unsigned t2 = i4 >> 13;
  const unsigned bc = t2 / 48u;
  const float4 a  = ((const float4*)av)[i4];
  const float4 dl = ((const float4*)delta)[(size_t)bc * 8192u + n4];
  ((float4*)out)[i4] = make_float4(a.x + dl.x, a.y + dl.y, a.z + dl.z, a.w + dl.w);
}

// ===========================================================================
extern "C" void kernel_launch(void* const* d_in, const int* in_sizes, int n_in,
                              void* d_out, int out_size, void* d_ws, size_t ws_size,
                              hipStream_t stream) {
  const float* attn_vol = (const float*)d_in[0];
  const float* feat     = (const float*)d_in[1];
  const float* disp     = (const float*)d_in[2];
  const float* Wq       = (const float*)d_in[3];
  const float* Wk       = (const float*)d_in[4];
  const float* Wv       = (const float*)d_in[5];
  const float* Wo       = (const float*)d_in[6];
  float* out            = (float*)d_out;
  float* ws             = (float*)d_ws;
  const int nf4 = out_size / 4;

  if (ws_size >= NEED_BYTES) {
    float* kvq = ws + WS_KVQ;
    float* wt  = ws + WS_WT;
    float* wot = ws + WS_WOT;
    hipLaunchKernelGGL(prep_new_k, dim3(512), dim3(256), 0, stream,
                       Wq, Wk, Wv, Wo, wt, wot, kvq);
    hipLaunchKernelGGL(qkv_new_k, dim3(Nn / 64, Bc), dim3(256), 0, stream,
                       feat, wt, kvq);
    hipLaunchKernelGGL(attn_fused_k, dim3(Nn / 64, Bc), dim3(256), 0, stream,
                       kvq, wot, disp, attn_vol, out);
  } else {
    float* kv    = ws + OWS_KV;
    float* delta = ws + OWS_DELTA;
    float* wtkv  = ws + OWS_WTKV;
    float* wtq   = ws + OWS_WTQ;
    hipLaunchKernelGGL(prep_weights_k, dim3(40), dim3(256), 0, stream,
                       Wq, Wk, Wv, wtkv, wtq);
    hipLaunchKernelGGL(qkv_k, dim3(Nn / 64, Bc), dim3(256), 0, stream,
                       feat, wtkv, kv);
    hipLaunchKernelGGL(attn_k, dim3(Nn / 256, Bc), dim3(256), 0, stream,
                       feat, kv, wtq, Wo, disp, delta);
    hipLaunchKernelGGL(add_k, dim3(nf4 / 256), dim3(256), 0, stream,
                       attn_vol, delta, out);
  }
}